// Round 1
// baseline (306.532 us; speedup 1.0000x reference)
//
#include <hip/hip_runtime.h>
#include <math.h>

#define BDIM 512   // one thread per output time-step
#define NCH 128    // N output channels
#define C_IN 64    // input channels
#define L_IN 16384 // input length
#define WIDTH 512

__global__ __launch_bounds__(BDIM) void extract_slices_kernel(
    const float* __restrict__ x,            // (64, 64, 16384)
    const float* __restrict__ channel_params, // (128,)
    const float* __restrict__ offset_params,  // (128,)
    float* __restrict__ out)                // (64, 128, 512)
{
    const int bn = blockIdx.x;       // b*128 + n
    const int b  = bn >> 7;
    const int n  = bn & 127;
    const int j  = threadIdx.x;      // 0..511

    // Per-n parameters (computed redundantly per thread; cheap vs memory)
    const float cp = channel_params[n];
    const float op = offset_params[n];

    // sigmoid with precise expf to match jax.nn.sigmoid as closely as possible
    const float sc = 1.0f / (1.0f + expf(-cp));
    const float so = 1.0f / (1.0f + expf(-op));

    const float desired = sc * (float)(C_IN - 1);
    const int   fc = (int)floorf(desired);
    const int   cc = min(fc + 1, C_IN - 1);
    const float wc = desired - (float)fc;

    const float t0 = so * (float)(L_IN - WIDTH);
    const int   p0 = (int)floorf(t0);
    const float wt = t0 - (float)p0;   // frac(t0); constant across j since j is integer

    const float* rowf = x + ((size_t)b * C_IN + fc) * L_IN;
    const float* rowc = x + ((size_t)b * C_IN + cc) * L_IN;

    const int pf = p0 + j;                 // floor position for this output
    const int pc = min(pf + 1, L_IN - 1);  // ceil position (clamp is a no-op in practice)

    // channel lerp at pf and pc (same op order as reference: a + w*(b-a))
    const float af = rowf[pf];
    const float bf = rowc[pf];
    const float ac = rowf[pc];
    const float bc = rowc[pc];

    const float xch_f = af + wc * (bf - af);
    const float xch_c = ac + wc * (bc - ac);

    out[((size_t)b * NCH + n) * WIDTH + j] = xch_f + wt * (xch_c - xch_f);
}

extern "C" void kernel_launch(void* const* d_in, const int* in_sizes, int n_in,
                              void* d_out, int out_size, void* d_ws, size_t ws_size,
                              hipStream_t stream) {
    const float* x  = (const float*)d_in[0];
    const float* cp = (const float*)d_in[1];
    const float* op = (const float*)d_in[2];
    float* out = (float*)d_out;

    const int B = 64;
    dim3 grid(B * NCH);   // 8192 blocks, one per (b, n)
    dim3 block(BDIM);
    extract_slices_kernel<<<grid, block, 0, stream>>>(x, cp, op, out);
}